// Round 1
// baseline (3057.357 us; speedup 1.0000x reference)
//
#include <hip/hip_runtime.h>

#define B 8
#define N 8192
#define S 2048
#define K 32

// Exact (no-FMA, left-to-right) squared distance to match numpy/XLA fp32:
// ((dx*dx + dy*dy) + dz*dz). FPS argmax is a chaotic recurrence; any ulp
// difference can diverge the selected-center sequence.
__device__ __forceinline__ float sqdist3(float ax, float ay, float az,
                                         float bx, float by, float bz) {
    float dx = ax - bx, dy = ay - by, dz = az - bz;
    return __fadd_rn(__fadd_rn(__fmul_rn(dx, dx), __fmul_rn(dy, dy)),
                     __fmul_rn(dz, dz));
}

// ---------------------------------------------------------------------------
// FPS: one block per batch, 1024 threads, 8 points/thread in registers.
// Writes centers coords [B,S,3] into `centers` (tail region of d_out).
// ---------------------------------------------------------------------------
__global__ __launch_bounds__(1024) void fps_kernel(const float* __restrict__ xyz,
                                                   float* __restrict__ centers) {
    const int b = blockIdx.x;
    const float* xb = xyz + (size_t)b * N * 3;
    const int t = threadIdx.x;

    float x[8], y[8], z[8], md[8];
#pragma unroll
    for (int i = 0; i < 8; ++i) {
        int p = t + (i << 10);           // p = t + 1024*i (coalesced load)
        x[i] = xb[3 * p + 0];
        y[i] = xb[3 * p + 1];
        z[i] = xb[3 * p + 2];
        md[i] = INFINITY;
    }

    __shared__ float s_px, s_py, s_pz;
    __shared__ unsigned s_gidx;
    __shared__ float s_wmax[16];

    float* cb = centers + (size_t)b * S * 3;

    // step 0: reference always picks index 0 first
    if (t == 0) {
        s_px = x[0]; s_py = y[0]; s_pz = z[0];
        cb[0] = x[0]; cb[1] = y[0]; cb[2] = z[0];
        s_gidx = 0xFFFFFFFFu;
    }
    __syncthreads();

    const int wid = t >> 6;
    for (int s = 1; s < S; ++s) {
        const float px = s_px, py = s_py, pz = s_pz;
        float vmax = -INFINITY;
#pragma unroll
        for (int i = 0; i < 8; ++i) {
            float d = sqdist3(x[i], y[i], z[i], px, py, pz);
            float m = fminf(md[i], d);
            md[i] = m;
            vmax = fmaxf(vmax, m);
        }
        // wave max (fmaxf returns one of its args -> value stays exact)
#pragma unroll
        for (int o = 32; o; o >>= 1) vmax = fmaxf(vmax, __shfl_xor(vmax, o));
        if ((t & 63) == 0) s_wmax[wid] = vmax;
        __syncthreads();                                   // barrier A
        float gmax = s_wmax[t & 15];
#pragma unroll
        for (int o = 8; o; o >>= 1) gmax = fmaxf(gmax, __shfl_xor(gmax, o));

        // first-index tie-break, matching np.argmax: smallest point index
        // among md[i] == gmax. Descending i loop => smallest local p wins.
        unsigned lc = 0xFFFFFFFFu;
#pragma unroll
        for (int i = 7; i >= 0; --i)
            if (md[i] == gmax) lc = (unsigned)(t + (i << 10));
        if (lc != 0xFFFFFFFFu) atomicMin(&s_gidx, lc);
        __syncthreads();                                   // barrier B1
        const unsigned gidx = s_gidx;

        // owner thread publishes coords from registers (no global re-read)
#pragma unroll
        for (int i = 0; i < 8; ++i) {
            if ((unsigned)(t + (i << 10)) == gidx) {
                s_px = x[i]; s_py = y[i]; s_pz = z[i];
                float* c = cb + 3 * s;
                c[0] = x[i]; c[1] = y[i]; c[2] = z[i];
            }
        }
        __syncthreads();                                   // barrier B2
        if (t == 0) s_gidx = 0xFFFFFFFFu;  // reset; ordered vs next atomicMin
                                           // by barrier A of the next step
    }
}

// ---------------------------------------------------------------------------
// KNN + gather: one wave per center. Top-32 held SORTED across lanes 0..31 as
// packed u64 (dist_bits<<32 | idx) -> lexicographic (d, idx) order == stable
// top_k tie semantics. Insert = wave-wide shfl_up shift (O(1) per insert).
// ---------------------------------------------------------------------------
__global__ __launch_bounds__(256) void knn_kernel(const float* __restrict__ xyz,
                                                  const float* __restrict__ centers,
                                                  float* __restrict__ out) {
    const int gw = (int)((blockIdx.x * blockDim.x + threadIdx.x) >> 6);
    const int lane = (int)(threadIdx.x & 63);
    const int b = gw >> 11;        // gw / S
    const int s = gw & (S - 1);
    const float* xb = xyz + (size_t)b * N * 3;
    const float* c = centers + (size_t)(b * S + s) * 3;
    const float cx = c[0], cy = c[1], cz = c[2];

    unsigned long long P = ~0ULL;     // lanes 0..31: sorted top-32 (asc)
    unsigned long long tau = ~0ULL;   // current worst kept = P at lane 31

    for (int i = 0; i < N / 64; ++i) {
        const int p = (i << 6) + lane;
        const float* q = xb + 3 * p;
        const float d = sqdist3(q[0], q[1], q[2], cx, cy, cz);
        const unsigned long long cand =
            ((unsigned long long)__float_as_uint(d) << 32) | (unsigned)p;
        bool alive = cand < tau;
        unsigned long long mask = __ballot(alive);
        while (mask) {
            const int src = __builtin_ctzll(mask);
            const unsigned long long bc = __shfl(cand, src);
            unsigned long long up = __shfl_up(P, 1);
            if (lane == 0) up = bc;
            const bool gt = P > bc;  // strict: bc < tau guarantees lane31 evicts
            const unsigned long long shifted = (up > bc) ? up : bc;
            P = gt ? shifted : P;
            tau = __shfl(P, 31);
            if (lane == src) alive = false;
            alive = alive && (cand < tau);
            mask = __ballot(alive);
        }
    }

    // epilogue: lane k = k-th nearest (ascending d, ties by index = top_k order)
    if (lane < K) {
        const unsigned nidx = (unsigned)P;
        const float* q = xb + 3 * nidx;
        float* o = out + ((size_t)(b * S + s) * K + lane) * 3;
        o[0] = q[0] - cx;
        o[1] = q[1] - cy;
        o[2] = q[2] - cz;
    }
}

extern "C" void kernel_launch(void* const* d_in, const int* in_sizes, int n_in,
                              void* d_out, int out_size, void* d_ws, size_t ws_size,
                              hipStream_t stream) {
    const float* xyz = (const float*)d_in[0];
    float* out = (float*)d_out;                         // neighborhood [B,S,K,3]
    float* centers = out + (size_t)B * S * K * 3;       // centers [B,S,3]

    fps_kernel<<<B, 1024, 0, stream>>>(xyz, centers);
    knn_kernel<<<(B * S) / 4, 256, 0, stream>>>(xyz, centers, out);
}